// Round 1
// baseline (29875.739 us; speedup 1.0000x reference)
//
#include <hip/hip_runtime.h>
#include <hip/hip_cooperative_groups.h>
#include <math.h>

namespace cg = cooperative_groups;

// Problem dims
#define B_  32
#define S_  256
#define I_  256
#define H_  512
#define N_  128
#define C_  64
#define O_  256
#define P_  268          // 4*C + 12
#define K_  832          // I + C + H
#define HB  (H_*B_)      // 16384
#define EPSX 1e-8f

// Workspace layout (float offsets). Total 7,276,928 floats = 29.1 MB.
#define OFF_XT   0
#define SZ_XT    (S_*I_*B_)                 // 2,097,152  x transposed [t][k][b]
#define OFF_HA   (OFF_XT + SZ_XT)
#define SZ_HA    ((S_+1)*H_*B_)             // 4,210,688  h history [t][k][b]
#define OFF_RA   (OFF_HA + SZ_HA)
#define SZ_RA    ((S_+1)*C_*B_)             // 526,336    r history [t][k][b]
#define OFF_CT   (OFF_RA + SZ_RA)
#define SZ_CT    (H_*B_)                    // LSTM cell state [k][b]
#define OFF_M    (OFF_CT + SZ_CT)
#define SZ_M     (B_*N_*C_)                 // memory [b][n][c]
#define OFF_WR   (OFF_M + SZ_M)
#define SZ_W     (B_*N_)                    // read weights [b][n]
#define OFF_WW   (OFF_WR + SZ_W)
#define OFF_PT   (OFF_WW + SZ_W)
#define SZ_PT    (P_*B_)                    // head params [row][b]
#define OFF_WOT  (OFF_PT + SZ_PT)
#define SZ_WOT   ((H_+C_)*O_)               // W_out transposed [k][o]

__device__ __forceinline__ float sigm(float x) { return 1.f / (1.f + expf(-x)); }
__device__ __forceinline__ float splus(float x) {
    // stable softplus: max(x,0) + log1p(exp(-|x|))
    return fmaxf(x, 0.f) + log1pf(expf(-fabsf(x)));
}

// ---------------- prep: transpose x & W_out, init state ----------------
__global__ __launch_bounds__(256)
void prep_kernel(const float* __restrict__ x, const float* __restrict__ Wout,
                 float* __restrict__ ws)
{
    int g = blockIdx.x * 256 + threadIdx.x;
    if (g < SZ_XT) {                       // xT[t][k][b] = x[b][t][k]
        int b = g & 31, k = (g >> 5) & 255, t = g >> 13;
        ws[OFF_XT + g] = x[b * (S_*I_) + t * I_ + k];
        return;
    }
    g -= SZ_XT;
    if (g < SZ_WOT) {                      // WoT[k][o] = W_out[o][k]
        int o = g & 255, k = g >> 8;
        ws[OFF_WOT + g] = Wout[o * (H_ + C_) + k];
        return;
    }
    g -= SZ_WOT;
    if (g < HB)      { ws[OFF_HA + g] = 0.f;   return; }   // h slot 0
    g -= HB;
    if (g < C_*B_)   { ws[OFF_RA + g] = 0.f;   return; }   // r slot 0
    g -= C_*B_;
    if (g < SZ_CT)   { ws[OFF_CT + g] = 0.f;   return; }   // c
    g -= SZ_CT;
    if (g < SZ_M)    { ws[OFF_M  + g] = 0.01f; return; }   // M
    g -= SZ_M;
    if (g < SZ_W)    { ws[OFF_WR + g] = ((g & (N_-1)) == 0) ? 1.f : 0.f; return; }
    g -= SZ_W;
    if (g < SZ_W)    { ws[OFF_WW + g] = ((g & (N_-1)) == 0) ? 1.f : 0.f; return; }
}

// ---------------- persistent sequential loop (cooperative) ----------------
// 256 blocks x 512 threads, 1 block/CU.
// Block bi: ug = bi>>1 owns units [4ug,4ug+4) (16 gate rows in LDS), bh = bi&1
// owns batches [16bh,16bh+16). Blocks 0..31 additionally do addressing for
// batch bi in phase 3. Blocks (+0..11) do head rows 256+bi in phase 2.
__global__ __launch_bounds__(512)
void ntm_loop(const float* __restrict__ Wih, const float* __restrict__ Whh,
              const float* __restrict__ bl,  const float* __restrict__ Whead,
              const float* __restrict__ bhead, float* __restrict__ ws)
{
    float* xT  = ws + OFF_XT;
    float* hA  = ws + OFF_HA;
    float* rA  = ws + OFF_RA;
    float* cT  = ws + OFF_CT;
    float* Mem = ws + OFF_M;
    float* wR  = ws + OFF_WR;
    float* wW  = ws + OFF_WW;
    float* pT  = ws + OFF_PT;

    // LDS: 59904 + 1072 + 512*4 = 63,024 B  (< 64 KB)
    __shared__ float Wt[K_ * 18];     // gate rows transposed, stride 18 (bank-spread, 8B-aligned pairs)
    __shared__ float p_lds[P_];
    __shared__ float sbuf[128];
    __shared__ float wtmp[128];
    __shared__ float wldsR[128];
    __shared__ float wldsW[128];

    const int tid = threadIdx.x;
    const int bi  = blockIdx.x;
    const int ug  = bi >> 1;
    const int bh  = bi & 1;

    // Load this block's 16 gate rows into LDS (once per launch).
    // r_local = u_local*4 + gate_type ; global row = gate_type*512 + ug*4 + u_local
    for (int idx = tid; idx < K_ * 16; idx += 512) {
        int rl = idx & 15, k = idx >> 4;
        int row = (rl & 3) * H_ + ug * 4 + (rl >> 2);
        float v = (k < I_ + C_) ? Wih[row * (I_ + C_) + k]
                                : Whh[row * H_ + (k - (I_ + C_))];
        Wt[k * 18 + rl] = v;
    }
    __syncthreads();

    cg::grid_group grid = cg::this_grid();

    // thread tiling for gates: 32 pairs (4 unit-rows x 8.. -> rg in[0,4), bg in[0,4)) x 32 split-K lanes
    const int pair = tid >> 5;        // 0..15
    const int ks   = tid & 31;        // split-K lane
    const int rg   = pair >> 2;       // u_local 0..3
    const int bg   = pair & 3;        // batch quad 0..3
    const int b0   = bh * 16 + bg * 4;

    for (int t = 0; t < S_; ++t) {
        // ---------------- P1: gates GEMM + LSTM update -> h[t+1], c ----------------
        {
            float acc[4][4] = {{0,0,0,0},{0,0,0,0},{0,0,0,0},{0,0,0,0}};
            const float* xs = xT + (size_t)t * I_ * B_;
            const float* rs = rA + (size_t)t * C_ * B_;
            const float* hs = hA + (size_t)t * HB;
            // k = ks + 32*i ; i<8: x-part, i<10: r-part, else h-part (exact range splits)
            #pragma unroll
            for (int i = 0; i < 26; ++i) {
                const int k = ks + (i << 5);
                const float* ap;
                if (i < 8)       ap = xs + k * B_ + b0;
                else if (i < 10) ap = rs + (k - I_) * B_ + b0;
                else             ap = hs + (k - I_ - C_) * B_ + b0;
                const float4 a   = *(const float4*)ap;
                const float2 w01 = *(const float2*)&Wt[k * 18 + (rg << 2)];
                const float2 w23 = *(const float2*)&Wt[k * 18 + (rg << 2) + 2];
                const float wv[4] = {w01.x, w01.y, w23.x, w23.y};
                const float av[4] = {a.x, a.y, a.z, a.w};
                #pragma unroll
                for (int j = 0; j < 4; ++j)
                    #pragma unroll
                    for (int bb = 0; bb < 4; ++bb)
                        acc[j][bb] += wv[j] * av[bb];
            }
            // reduce over 32 split-K lanes (butterfly)
            #pragma unroll
            for (int j = 0; j < 4; ++j)
                #pragma unroll
                for (int bb = 0; bb < 4; ++bb) {
                    float v = acc[j][bb];
                    v += __shfl_xor(v, 16, 64);
                    v += __shfl_xor(v, 8, 64);
                    v += __shfl_xor(v, 4, 64);
                    v += __shfl_xor(v, 2, 64);
                    v += __shfl_xor(v, 1, 64);
                    acc[j][bb] = v;
                }
            if (ks == 0) {
                const int unit = ug * 4 + rg;
                #pragma unroll
                for (int bb = 0; bb < 4; ++bb) {
                    const int b = b0 + bb;
                    float gi = acc[0][bb] + bl[unit];
                    float gf = acc[1][bb] + bl[H_ + unit];
                    float gg = acc[2][bb] + bl[2 * H_ + unit];
                    float go = acc[3][bb] + bl[3 * H_ + unit];
                    float cN = sigm(gf) * cT[unit * B_ + b] + sigm(gi) * tanhf(gg);
                    float hN = sigm(go) * tanhf(cN);
                    cT[unit * B_ + b] = cN;
                    hA[(size_t)(t + 1) * HB + unit * B_ + b] = hN;
                }
            }
        }
        grid.sync();

        // ---------------- P2: head GEMM p = W_head @ h + b_head ----------------
        {
            const float* hs = hA + (size_t)(t + 1) * HB;
            const int b   = tid >> 4;     // 0..31
            const int ksh = tid & 15;
            #pragma unroll
            for (int rep = 0; rep < 2; ++rep) {
                const int nrow = (rep == 0) ? bi : ((bi < P_ - 256) ? 256 + bi : -1);
                if (nrow >= 0) {
                    const float* wrow = Whead + nrow * H_;
                    float acc = 0.f;
                    #pragma unroll 4
                    for (int i = 0; i < 32; ++i) {
                        const int k = ksh + 16 * i;
                        acc += wrow[k] * hs[k * B_ + b];
                    }
                    acc += __shfl_xor(acc, 8, 64);
                    acc += __shfl_xor(acc, 4, 64);
                    acc += __shfl_xor(acc, 2, 64);
                    acc += __shfl_xor(acc, 1, 64);
                    if (ksh == 0) pT[nrow * B_ + b] = acc + bhead[nrow];
                }
            }
        }
        grid.sync();

        // ---------------- P3: addressing + memory write + read (blocks 0..31) ----------------
        if (bi < B_) {
            const int b = bi;
            float* Mb = Mem + (size_t)b * N_ * C_;
            for (int idx = tid; idx < P_; idx += 512) p_lds[idx] = pT[idx * B_ + b];
            __syncthreads();

            // pass 0: read head (params at 0), pass 1: write head (params at 70)
            for (int pass = 0; pass < 2; ++pass) {
                const int o = pass ? 70 : 0;
                const float beta  = splus(p_lds[o + 64]);
                const float gate  = sigm(p_lds[o + 65]);
                float sa = p_lds[o + 66], sbv = p_lds[o + 67], sc = p_lds[o + 68];
                float sm3 = fmaxf(sa, fmaxf(sbv, sc));
                float ea = expf(sa - sm3), eb = expf(sbv - sm3), ec = expf(sc - sm3);
                float es3 = ea + eb + ec;
                const float s0 = ea / es3, s1 = eb / es3, s2 = ec / es3;
                const float gamma = 1.f + splus(p_lds[o + 69]);
                float kk = 0.f;
                #pragma unroll 8
                for (int c = 0; c < C_; ++c) { float kv = p_lds[o + c]; kk += kv * kv; }
                const float knorm = sqrtf(kk) + EPSX;

                const int n = tid;
                float z = 0.f, ev = 0.f;
                if (tid < N_) {
                    float dot = 0.f, mm = 0.f;
                    #pragma unroll
                    for (int c = 0; c < C_; c += 4) {
                        float4 m4 = *(const float4*)&Mb[n * C_ + c];
                        dot += m4.x * p_lds[o + c]     + m4.y * p_lds[o + c + 1]
                             + m4.z * p_lds[o + c + 2] + m4.w * p_lds[o + c + 3];
                        mm  += m4.x * m4.x + m4.y * m4.y + m4.z * m4.z + m4.w * m4.w;
                    }
                    z = beta * (dot / ((sqrtf(mm) + EPSX) * knorm));
                }
                // softmax over n=128 (stable)
                if (tid < N_) sbuf[tid] = z;
                __syncthreads();
                for (int st = 64; st > 0; st >>= 1) {
                    if (tid < st && tid + st < N_) sbuf[tid] = fmaxf(sbuf[tid], sbuf[tid + st]);
                    __syncthreads();
                }
                const float zmax = sbuf[0];
                __syncthreads();
                if (tid < N_) { ev = expf(z - zmax); sbuf[tid] = ev; }
                __syncthreads();
                for (int st = 64; st > 0; st >>= 1) {
                    if (tid < st && tid + st < N_) sbuf[tid] += sbuf[tid + st];
                    __syncthreads();
                }
                const float esum = sbuf[0];
                __syncthreads();
                float* wprev = pass ? wW : wR;
                if (tid < N_) {
                    float wc = ev / esum;
                    wtmp[n] = gate * wc + (1.f - gate) * wprev[b * N_ + n];
                }
                __syncthreads();
                float wp = 0.f;
                if (tid < N_) {
                    float wsft = s0 * wtmp[(n + 1) & (N_-1)] + s1 * wtmp[n]
                               + s2 * wtmp[(n - 1) & (N_-1)];
                    wp = powf(wsft + EPSX, gamma);
                    sbuf[tid] = wp;
                }
                __syncthreads();
                for (int st = 64; st > 0; st >>= 1) {
                    if (tid < st && tid + st < N_) sbuf[tid] += sbuf[tid + st];
                    __syncthreads();
                }
                const float psum = sbuf[0];
                __syncthreads();
                if (tid < N_) {
                    float wn = wp / psum;
                    if (pass) { wldsW[n] = wn; wW[b * N_ + n] = wn; }
                    else      { wldsR[n] = wn; wR[b * N_ + n] = wn; }
                }
                __syncthreads();
            }

            // M = M*(1 - w_w e) + w_w a   (erase+add)
            for (int idx = tid; idx < (N_ * C_) / 4; idx += 512) {
                const int n = idx >> 4;
                const int c = (idx & 15) << 2;
                const float wwn = wldsW[n];
                float4 m4 = *(float4*)&Mb[n * C_ + c];
                m4.x = m4.x * (1.f - wwn * sigm(p_lds[140 + c]))     + wwn * p_lds[204 + c];
                m4.y = m4.y * (1.f - wwn * sigm(p_lds[140 + c + 1])) + wwn * p_lds[204 + c + 1];
                m4.z = m4.z * (1.f - wwn * sigm(p_lds[140 + c + 2])) + wwn * p_lds[204 + c + 2];
                m4.w = m4.w * (1.f - wwn * sigm(p_lds[140 + c + 3])) + wwn * p_lds[204 + c + 3];
                *(float4*)&Mb[n * C_ + c] = m4;
            }
            __threadfence_block();
            __syncthreads();

            // r = w_r @ M_new
            {
                const int c = tid >> 3, ns = tid & 7;
                float acc = 0.f;
                #pragma unroll
                for (int i = 0; i < 16; ++i) {
                    const int n = ns + 8 * i;
                    acc += wldsR[n] * Mb[n * C_ + c];
                }
                acc += __shfl_xor(acc, 4, 64);
                acc += __shfl_xor(acc, 2, 64);
                acc += __shfl_xor(acc, 1, 64);
                if (ns == 0) rA[(size_t)(t + 1) * C_ * B_ + c * B_ + b] = acc;
            }
        }
        grid.sync();
    }
}

// ---------------- final output GEMM: out[b][t][:] = [h_t; r_t] @ W_out^T + b_out ----------------
__global__ __launch_bounds__(256)
void out_kernel(const float* __restrict__ ws, const float* __restrict__ bout,
                float* __restrict__ out)
{
    __shared__ float actL[(H_ + C_) * 16];   // 36,864 B
    const float* hA  = ws + OFF_HA;
    const float* rA  = ws + OFF_RA;
    const float* WoT = ws + OFF_WOT;
    const int t   = blockIdx.x >> 1;
    const int bh  = blockIdx.x & 1;
    const int tid = threadIdx.x;

    for (int idx = tid; idx < (H_ + C_) * 16; idx += 256) {
        const int k = idx >> 4, bl2 = idx & 15, b = bh * 16 + bl2;
        float v = (k < H_) ? hA[(size_t)(t + 1) * HB + k * B_ + b]
                           : rA[(size_t)(t + 1) * C_ * B_ + (k - H_) * B_ + b];
        actL[k * 16 + bl2] = v;
    }
    __syncthreads();

    const int ot = tid & 63, bt = tid >> 6;    // wave-uniform bt -> LDS broadcast
    const int o0 = ot * 4, bl0 = bt * 4;
    float acc[4][4] = {{0,0,0,0},{0,0,0,0},{0,0,0,0},{0,0,0,0}};
    for (int k = 0; k < H_ + C_; ++k) {
        const float4 w4 = *(const float4*)&WoT[k * O_ + o0];
        const float4 a4 = *(const float4*)&actL[k * 16 + bl0];
        const float wv[4] = {w4.x, w4.y, w4.z, w4.w};
        const float av[4] = {a4.x, a4.y, a4.z, a4.w};
        #pragma unroll
        for (int j = 0; j < 4; ++j)
            #pragma unroll
            for (int bb = 0; bb < 4; ++bb)
                acc[j][bb] += wv[j] * av[bb];
    }
    const float4 bo = *(const float4*)&bout[o0];
    #pragma unroll
    for (int bb = 0; bb < 4; ++bb) {
        const int b = bh * 16 + bl0 + bb;
        float4 res;
        res.x = acc[0][bb] + bo.x;
        res.y = acc[1][bb] + bo.y;
        res.z = acc[2][bb] + bo.z;
        res.w = acc[3][bb] + bo.w;
        *(float4*)&out[((size_t)b * S_ + t) * O_ + o0] = res;
    }
}

extern "C" void kernel_launch(void* const* d_in, const int* in_sizes, int n_in,
                              void* d_out, int out_size, void* d_ws, size_t ws_size,
                              hipStream_t stream)
{
    const float* x    = (const float*)d_in[0];
    const float* Wih  = (const float*)d_in[1];
    const float* Whh  = (const float*)d_in[2];
    const float* bl   = (const float*)d_in[3];
    const float* Whd  = (const float*)d_in[4];
    const float* bhd  = (const float*)d_in[5];
    const float* Wout = (const float*)d_in[6];
    const float* bout = (const float*)d_in[7];
    float* ws  = (float*)d_ws;    // needs 29.1 MB
    float* out = (float*)d_out;

    prep_kernel<<<9960, 256, 0, stream>>>(x, Wout, ws);

    void* args[] = { (void*)&Wih, (void*)&Whh, (void*)&bl,
                     (void*)&Whd, (void*)&bhd, (void*)&ws };
    hipLaunchCooperativeKernel((void*)ntm_loop, dim3(256), dim3(512), args, 0, stream);

    out_kernel<<<512, 256, 0, stream>>>(ws, bout, out);
}

// Round 3
// 20130.170 us; speedup vs baseline: 1.4841x; 1.4841x over previous
//
#include <hip/hip_runtime.h>
#include <hip/hip_cooperative_groups.h>
#include <math.h>

// Problem dims
#define B_  32
#define S_  256
#define I_  256
#define H_  512
#define N_  128
#define C_  64
#define O_  256
#define P_  268          // 4*C + 12
#define K_  832          // I + C + H
#define HB  (H_*B_)      // 16384
#define EPSX 1e-8f
#define NBLK 256

// Workspace layout (float offsets). Total 7,268,864 floats = 29.08 MB.
#define OFF_XT   0
#define SZ_XT    (S_*I_*B_)                 // 2,097,152  x transposed [t][k][b]
#define OFF_HA   (OFF_XT + SZ_XT)
#define SZ_HA    ((S_+1)*H_*B_)             // 4,210,688  h history [t][k][b]
#define OFF_RA   (OFF_HA + SZ_HA)
#define SZ_RA    ((S_+1)*C_*B_)             // 526,336    r history [t][k][b]
#define OFF_CT   (OFF_RA + SZ_RA)
#define SZ_CT    (H_*B_)                    // LSTM cell state [k][b]
#define OFF_M    (OFF_CT + SZ_CT)
#define SZ_M     (B_*N_*C_)                 // memory [b][n][c]
#define OFF_WR   (OFF_M + SZ_M)
#define SZ_W     (B_*N_)                    // read weights [b][n]
#define OFF_WW   (OFF_WR + SZ_W)
#define OFF_BAR  (OFF_WW + SZ_W)
#define SZ_BAR   512                        // arrive[256] + release + pad
#define OFF_WOT  (OFF_BAR + SZ_BAR)
#define SZ_WOT   ((H_+C_)*O_)               // W_out transposed [k][o]

__device__ __forceinline__ float sigm(float x) { return 1.f / (1.f + expf(-x)); }
__device__ __forceinline__ float splus(float x) {
    return fmaxf(x, 0.f) + log1pf(expf(-fabsf(x)));  // stable softplus
}

// ---- custom grid barrier -------------------------------------------------
// arrive[bi] slots + single release flag. Master = block NBLK-1 (idle in
// phase B). Relaxed agent-scope spins (no per-iteration cache invalidate);
// one agent-scope fence at each edge. Coherence point = L3, not HBM.
// (__hip_atomic_fence is not exposed by this ROCm build; use the clang
//  builtin __builtin_amdgcn_fence, which it lowers to anyway.)
__device__ __forceinline__ void gbar(unsigned* arrive, unsigned* release,
                                     int bi, int tid, unsigned seq)
{
    __syncthreads();
    if (bi == NBLK - 1) {
        if (tid < NBLK - 1) {
            while (__hip_atomic_load(&arrive[tid], __ATOMIC_RELAXED,
                                     __HIP_MEMORY_SCOPE_AGENT) < seq)
                __builtin_amdgcn_s_sleep(1);
        }
        __syncthreads();
        if (tid == 0) {
            __builtin_amdgcn_fence(__ATOMIC_ACQ_REL, "agent");
            __hip_atomic_store(release, seq, __ATOMIC_RELAXED,
                               __HIP_MEMORY_SCOPE_AGENT);
        }
        __syncthreads();
        __builtin_amdgcn_fence(__ATOMIC_ACQUIRE, "agent");
    } else {
        if (tid == 0) {
            __builtin_amdgcn_fence(__ATOMIC_RELEASE, "agent");
            __hip_atomic_store(&arrive[bi], seq, __ATOMIC_RELAXED,
                               __HIP_MEMORY_SCOPE_AGENT);
            while (__hip_atomic_load(release, __ATOMIC_RELAXED,
                                     __HIP_MEMORY_SCOPE_AGENT) < seq)
                __builtin_amdgcn_s_sleep(1);
        }
        __syncthreads();
        __builtin_amdgcn_fence(__ATOMIC_ACQUIRE, "agent");
    }
}

// ---------------- prep: transpose x & W_out, init state ----------------
__global__ __launch_bounds__(256)
void prep_kernel(const float* __restrict__ x, const float* __restrict__ Wout,
                 float* __restrict__ ws)
{
    int g = blockIdx.x * 256 + threadIdx.x;
    if (g < SZ_XT) {                       // xT[t][k][b] = x[b][t][k]
        int b = g & 31, k = (g >> 5) & 255, t = g >> 13;
        ws[OFF_XT + g] = x[b * (S_*I_) + t * I_ + k];
        return;
    }
    g -= SZ_XT;
    if (g < SZ_WOT) {                      // WoT[k][o] = W_out[o][k]
        int o = g & 255, k = g >> 8;
        ws[OFF_WOT + g] = Wout[o * (H_ + C_) + k];
        return;
    }
    g -= SZ_WOT;
    if (g < HB)      { ws[OFF_HA + g] = 0.f;   return; }   // h slot 0
    g -= HB;
    if (g < C_*B_)   { ws[OFF_RA + g] = 0.f;   return; }   // r slot 0
    g -= C_*B_;
    if (g < SZ_CT)   { ws[OFF_CT + g] = 0.f;   return; }   // c
    g -= SZ_CT;
    if (g < SZ_M)    { ws[OFF_M  + g] = 0.01f; return; }   // M
    g -= SZ_M;
    if (g < SZ_W)    { ws[OFF_WR + g] = ((g & (N_-1)) == 0) ? 1.f : 0.f; return; }
    g -= SZ_W;
    if (g < SZ_W)    { ws[OFF_WW + g] = ((g & (N_-1)) == 0) ? 1.f : 0.f; return; }
    g -= SZ_W;
    if (g < SZ_BAR)  { ws[OFF_BAR + g] = 0.f;  return; }   // barrier slots
}

// ---------------- persistent sequential loop (cooperative) ----------------
// 256 blocks x 512 threads, 1 block/CU, 2 syncs/step.
// Block bi: ug = bi>>1 owns units [4ug,4ug+4), bh = bi&1 owns batches
// [16bh,16bh+16) for the gates GEMM. Blocks 0..31 do the ENTIRE phase B
// (head GEMM + addressing + write + read) for batch bi — p never leaves LDS.
__global__ __launch_bounds__(512)
void ntm_loop(const float* __restrict__ Wih, const float* __restrict__ Whh,
              const float* __restrict__ bl,  const float* __restrict__ Whead,
              const float* __restrict__ bhead, float* __restrict__ ws)
{
    float* xT  = ws + OFF_XT;
    float* hA  = ws + OFF_HA;
    float* rA  = ws + OFF_RA;
    float* cT  = ws + OFF_CT;
    float* Mem = ws + OFF_M;
    float* wR  = ws + OFF_WR;
    float* wW  = ws + OFF_WW;
    unsigned* arrive  = (unsigned*)(ws + OFF_BAR);
    unsigned* release = (unsigned*)(ws + OFF_BAR + NBLK);

    // LDS: 59904 + 1072 + 2048 + 2048 = 65,072 B fits in 160 KiB/CU
    __shared__ float Wt[K_ * 18];     // gate rows transposed, stride 18
    __shared__ float p_lds[P_];
    __shared__ float sbuf[128];
    __shared__ float wtmp[128];
    __shared__ float wldsR[128];
    __shared__ float wldsW[128];
    __shared__ float h_lds[H_];       // phase-B h staging

    const int tid = threadIdx.x;
    const int bi  = blockIdx.x;
    const int ug  = bi >> 1;
    const int bh  = bi & 1;

    // Load this block's 16 gate rows into LDS (once per launch).
    for (int idx = tid; idx < K_ * 16; idx += 512) {
        int rl = idx & 15, k = idx >> 4;
        int row = (rl & 3) * H_ + ug * 4 + (rl >> 2);
        float v = (k < I_ + C_) ? Wih[row * (I_ + C_) + k]
                                : Whh[row * H_ + (k - (I_ + C_))];
        Wt[k * 18 + rl] = v;
    }

    const int pair = tid >> 5;        // 0..15
    const int ks   = tid & 31;        // split-K lane
    const int rg   = pair >> 2;       // u_local 0..3
    const int bg   = pair & 3;        // batch quad 0..3
    const int b0   = bh * 16 + bg * 4;

    unsigned seq = 0;

    for (int t = 0; t < S_; ++t) {
        // ---------------- P1: gates GEMM + LSTM update -> h[t+1], c ----------------
        {
            float acc[4][4] = {{0,0,0,0},{0,0,0,0},{0,0,0,0},{0,0,0,0}};
            const float* xs = xT + (size_t)t * I_ * B_;
            const float* rs = rA + (size_t)t * C_ * B_;
            const float* hs = hA + (size_t)t * HB;
            if (t == 0) __syncthreads();   // cover the Wt staging
            #pragma unroll
            for (int i = 0; i < 26; ++i) {
                const int k = ks + (i << 5);
                const float* ap;
                if (i < 8)       ap = xs + k * B_ + b0;
                else if (i < 10) ap = rs + (k - I_) * B_ + b0;
                else             ap = hs + (k - I_ - C_) * B_ + b0;
                const float4 a   = *(const float4*)ap;
                const float2 w01 = *(const float2*)&Wt[k * 18 + (rg << 2)];
                const float2 w23 = *(const float2*)&Wt[k * 18 + (rg << 2) + 2];
                const float wv[4] = {w01.x, w01.y, w23.x, w23.y};
                const float av[4] = {a.x, a.y, a.z, a.w};
                #pragma unroll
                for (int j = 0; j < 4; ++j)
                    #pragma unroll
                    for (int bb = 0; bb < 4; ++bb)
                        acc[j][bb] += wv[j] * av[bb];
            }
            #pragma unroll
            for (int j = 0; j < 4; ++j)
                #pragma unroll
                for (int bb = 0; bb < 4; ++bb) {
                    float v = acc[j][bb];
                    v += __shfl_xor(v, 16, 64);
                    v += __shfl_xor(v, 8, 64);
                    v += __shfl_xor(v, 4, 64);
                    v += __shfl_xor(v, 2, 64);
                    v += __shfl_xor(v, 1, 64);
                    acc[j][bb] = v;
                }
            if (ks == 0) {
                const int unit = ug * 4 + rg;
                #pragma unroll
                for (int bb = 0; bb < 4; ++bb) {
                    const int b = b0 + bb;
                    float gi = acc[0][bb] + bl[unit];
                    float gf = acc[1][bb] + bl[H_ + unit];
                    float gg = acc[2][bb] + bl[2 * H_ + unit];
                    float go = acc[3][bb] + bl[3 * H_ + unit];
                    float cN = sigm(gf) * cT[unit * B_ + b] + sigm(gi) * tanhf(gg);
                    float hN = sigm(go) * tanhf(cN);
                    cT[unit * B_ + b] = cN;
                    hA[(size_t)(t + 1) * HB + unit * B_ + b] = hN;
                }
            }
        }
        gbar(arrive, release, bi, tid, ++seq);

        // ---------------- Phase B (blocks 0..31): head GEMM + addressing + write + read ----
        if (bi < B_) {
            const int b = bi;
            float* Mb = Mem + (size_t)b * N_ * C_;
            const float* hs = hA + (size_t)(t + 1) * HB;

            // stage h[:,b] into LDS
            h_lds[tid] = hs[tid * B_ + b];
            __syncthreads();

            // head GEMM: p = W_head @ h + b_head, 2 threads per row (split-K)
            {
                const int sub  = tid & 1;        // k-half
                const int row0 = tid >> 1;       // 0..255
                const float* hb = &h_lds[sub * 256];
                {
                    const float* wrow = Whead + row0 * H_ + sub * 256;
                    float acc = 0.f;
                    #pragma unroll 8
                    for (int k2 = 0; k2 < 256; k2 += 4) {
                        const float4 w4 = *(const float4*)&wrow[k2];
                        acc += w4.x * hb[k2] + w4.y * hb[k2 + 1]
                             + w4.z * hb[k2 + 2] + w4.w * hb[k2 + 3];
                    }
                    acc += __shfl_xor(acc, 1, 64);
                    if (sub == 0) p_lds[row0] = acc + bhead[row0];
                }
                if (row0 < P_ - 256) {           // rows 256..267
                    const int row1 = row0 + 256;
                    const float* wrow = Whead + row1 * H_ + sub * 256;
                    float acc = 0.f;
                    #pragma unroll 8
                    for (int k2 = 0; k2 < 256; k2 += 4) {
                        const float4 w4 = *(const float4*)&wrow[k2];
                        acc += w4.x * hb[k2] + w4.y * hb[k2 + 1]
                             + w4.z * hb[k2 + 2] + w4.w * hb[k2 + 3];
                    }
                    acc += __shfl_xor(acc, 1, 64);
                    if (sub == 0) p_lds[row1] = acc + bhead[row1];
                }
            }
            __syncthreads();

            // addressing: pass 0 read head (params at 0), pass 1 write head (70)
            for (int pass = 0; pass < 2; ++pass) {
                const int o = pass ? 70 : 0;
                const float beta  = splus(p_lds[o + 64]);
                const float gate  = sigm(p_lds[o + 65]);
                float sa = p_lds[o + 66], sbv = p_lds[o + 67], sc = p_lds[o + 68];
                float sm3 = fmaxf(sa, fmaxf(sbv, sc));
                float ea = expf(sa - sm3), eb = expf(sbv - sm3), ec = expf(sc - sm3);
                float es3 = ea + eb + ec;
                const float s0 = ea / es3, s1 = eb / es3, s2 = ec / es3;
                const float gamma = 1.f + splus(p_lds[o + 69]);
                float kk = 0.f;
                #pragma unroll 8
                for (int c = 0; c < C_; ++c) { float kv = p_lds[o + c]; kk += kv * kv; }
                const float knorm = sqrtf(kk) + EPSX;

                const int n = tid;
                float z = 0.f, ev = 0.f;
                if (tid < N_) {
                    float dot = 0.f, mm = 0.f;
                    #pragma unroll
                    for (int c = 0; c < C_; c += 4) {
                        float4 m4 = *(const float4*)&Mb[n * C_ + c];
                        dot += m4.x * p_lds[o + c]     + m4.y * p_lds[o + c + 1]
                             + m4.z * p_lds[o + c + 2] + m4.w * p_lds[o + c + 3];
                        mm  += m4.x * m4.x + m4.y * m4.y + m4.z * m4.z + m4.w * m4.w;
                    }
                    z = beta * (dot / ((sqrtf(mm) + EPSX) * knorm));
                }
                if (tid < N_) sbuf[tid] = z;
                __syncthreads();
                for (int st = 64; st > 0; st >>= 1) {
                    if (tid < st && tid + st < N_) sbuf[tid] = fmaxf(sbuf[tid], sbuf[tid + st]);
                    __syncthreads();
                }
                const float zmax = sbuf[0];
                __syncthreads();
                if (tid < N_) { ev = expf(z - zmax); sbuf[tid] = ev; }
                __syncthreads();
                for (int st = 64; st > 0; st >>= 1) {
                    if (tid < st && tid + st < N_) sbuf[tid] += sbuf[tid + st];
                    __syncthreads();
                }
                const float esum = sbuf[0];
                __syncthreads();
                float* wprev = pass ? wW : wR;
                if (tid < N_) {
                    float wc = ev / esum;
                    wtmp[n] = gate * wc + (1.f - gate) * wprev[b * N_ + n];
                }
                __syncthreads();
                float wp = 0.f;
                if (tid < N_) {
                    float wsft = s0 * wtmp[(n + 1) & (N_-1)] + s1 * wtmp[n]
                               + s2 * wtmp[(n - 1) & (N_-1)];
                    wp = powf(wsft + EPSX, gamma);
                    sbuf[tid] = wp;
                }
                __syncthreads();
                for (int st = 64; st > 0; st >>= 1) {
                    if (tid < st && tid + st < N_) sbuf[tid] += sbuf[tid + st];
                    __syncthreads();
                }
                const float psum = sbuf[0];
                __syncthreads();
                if (tid < N_) {
                    float wn = wp / psum;
                    if (pass) { wldsW[n] = wn; wW[b * N_ + n] = wn; }
                    else      { wldsR[n] = wn; wR[b * N_ + n] = wn; }
                }
                __syncthreads();
            }

            // M = M*(1 - w_w e) + w_w a
            for (int idx = tid; idx < (N_ * C_) / 4; idx += 512) {
                const int n = idx >> 4;
                const int c = (idx & 15) << 2;
                const float wwn = wldsW[n];
                float4 m4 = *(float4*)&Mb[n * C_ + c];
                m4.x = m4.x * (1.f - wwn * sigm(p_lds[140 + c]))     + wwn * p_lds[204 + c];
                m4.y = m4.y * (1.f - wwn * sigm(p_lds[140 + c + 1])) + wwn * p_lds[204 + c + 1];
                m4.z = m4.z * (1.f - wwn * sigm(p_lds[140 + c + 2])) + wwn * p_lds[204 + c + 2];
                m4.w = m4.w * (1.f - wwn * sigm(p_lds[140 + c + 3])) + wwn * p_lds[204 + c + 3];
                *(float4*)&Mb[n * C_ + c] = m4;
            }
            __threadfence_block();
            __syncthreads();

            // r = w_r @ M_new
            {
                const int c = tid >> 3, ns = tid & 7;
                float acc = 0.f;
                #pragma unroll
                for (int i = 0; i < 16; ++i) {
                    const int n = ns + 8 * i;
                    acc += wldsR[n] * Mb[n * C_ + c];
                }
                acc += __shfl_xor(acc, 4, 64);
                acc += __shfl_xor(acc, 2, 64);
                acc += __shfl_xor(acc, 1, 64);
                if (ns == 0) rA[(size_t)(t + 1) * C_ * B_ + c * B_ + b] = acc;
            }
        }
        gbar(arrive, release, bi, tid, ++seq);
    }
}

// ---------------- final output GEMM ----------------
__global__ __launch_bounds__(256)
void out_kernel(const float* __restrict__ ws, const float* __restrict__ bout,
                float* __restrict__ out)
{
    __shared__ float actL[(H_ + C_) * 16];   // 36,864 B
    const float* hA  = ws + OFF_HA;
    const float* rA  = ws + OFF_RA;
    const float* WoT = ws + OFF_WOT;
    const int t   = blockIdx.x >> 1;
    const int bh  = blockIdx.x & 1;
    const int tid = threadIdx.x;

    for (int idx = tid; idx < (H_ + C_) * 16; idx += 256) {
        const int k = idx >> 4, bl2 = idx & 15, b = bh * 16 + bl2;
        float v = (k < H_) ? hA[(size_t)(t + 1) * HB + k * B_ + b]
                           : rA[(size_t)(t + 1) * C_ * B_ + (k - H_) * B_ + b];
        actL[k * 16 + bl2] = v;
    }
    __syncthreads();

    const int ot = tid & 63, bt = tid >> 6;
    const int o0 = ot * 4, bl0 = bt * 4;
    float acc[4][4] = {{0,0,0,0},{0,0,0,0},{0,0,0,0},{0,0,0,0}};
    for (int k = 0; k < H_ + C_; ++k) {
        const float4 w4 = *(const float4*)&WoT[k * O_ + o0];
        const float4 a4 = *(const float4*)&actL[k * 16 + bl0];
        const float wv[4] = {w4.x, w4.y, w4.z, w4.w};
        const float av[4] = {a4.x, a4.y, a4.z, a4.w};
        #pragma unroll
        for (int j = 0; j < 4; ++j)
            #pragma unroll
            for (int bb = 0; bb < 4; ++bb)
                acc[j][bb] += wv[j] * av[bb];
    }
    const float4 bo = *(const float4*)&bout[o0];
    #pragma unroll
    for (int bb = 0; bb < 4; ++bb) {
        const int b = bh * 16 + bl0 + bb;
        float4 res;
        res.x = acc[0][bb] + bo.x;
        res.y = acc[1][bb] + bo.y;
        res.z = acc[2][bb] + bo.z;
        res.w = acc[3][bb] + bo.w;
        *(float4*)&out[((size_t)b * S_ + t) * O_ + o0] = res;
    }
}

extern "C" void kernel_launch(void* const* d_in, const int* in_sizes, int n_in,
                              void* d_out, int out_size, void* d_ws, size_t ws_size,
                              hipStream_t stream)
{
    const float* x    = (const float*)d_in[0];
    const float* Wih  = (const float*)d_in[1];
    const float* Whh  = (const float*)d_in[2];
    const float* bl   = (const float*)d_in[3];
    const float* Whd  = (const float*)d_in[4];
    const float* bhd  = (const float*)d_in[5];
    const float* Wout = (const float*)d_in[6];
    const float* bout = (const float*)d_in[7];
    float* ws  = (float*)d_ws;    // needs 29.1 MB
    float* out = (float*)d_out;

    prep_kernel<<<9962, 256, 0, stream>>>(x, Wout, ws);

    void* args[] = { (void*)&Wih, (void*)&Whh, (void*)&bl,
                     (void*)&Whd, (void*)&bhd, (void*)&ws };
    (void)hipLaunchCooperativeKernel((void*)ntm_loop, dim3(256), dim3(512), args, 0, stream);

    out_kernel<<<512, 256, 0, stream>>>(ws, bout, out);
}

// Round 4
// 11301.537 us; speedup vs baseline: 2.6435x; 1.7812x over previous
//
#include <hip/hip_runtime.h>
#include <math.h>

// Problem dims
#define B_  32
#define S_  256
#define I_  256
#define H_  512
#define N_  128
#define C_  64
#define O_  256
#define P_  268          // 4*C + 12
#define K_  832          // I + C + H
#define HB  (H_*B_)      // 16384
#define EPSX 1e-8f
#define NBLK 256

// Workspace layout (float offsets).
#define OFF_XT   0
#define SZ_XT    (S_*I_*B_)                 // x transposed [t][k][b]
#define OFF_HA   (OFF_XT + SZ_XT)
#define SZ_HA    ((S_+1)*H_*B_)             // h history [t][k][b]
#define OFF_RA   (OFF_HA + SZ_HA)
#define SZ_RA    ((S_+1)*C_*B_)             // r history [t][k][b]
#define OFF_CT   (OFF_RA + SZ_RA)
#define SZ_CT    (H_*B_)                    // LSTM cell state [k][b] (block-private)
#define OFF_M    (OFF_CT + SZ_CT)
#define SZ_M     (B_*N_*C_)                 // memory [b][n][c]   (block-private)
#define OFF_WR   (OFF_M + SZ_M)
#define SZ_W     (B_*N_)                    // (unused now; kept for layout stability)
#define OFF_WW   (OFF_WR + SZ_W)
#define OFF_BAR  (OFF_WW + SZ_W)
#define SZ_BAR   512                        // cnt @ +0, release @ +64 (256B apart)
#define OFF_WOT  (OFF_BAR + SZ_BAR)
#define SZ_WOT   ((H_+C_)*O_)               // W_out transposed [k][o]

__device__ __forceinline__ float sigm(float x) { return 1.f / (1.f + expf(-x)); }
__device__ __forceinline__ float splus(float x) {
    return fmaxf(x, 0.f) + log1pf(expf(-fabsf(x)));  // stable softplus
}

// ---- fence-free grid barrier --------------------------------------------
// Shared data is published via agent-scope relaxed atomic stores (write-through
// to the L3 coherence point), so NO cache-flushing fence is needed here.
// Counting barrier: fetch_add on an L3-homed counter; last arriver sets the
// release flag. Data->flag ordering: s_waitcnt vmcnt(0) (compiler also drains
// vmcnt at the preceding __syncthreads in every wave).
__device__ __forceinline__ void gbar(unsigned* cnt, unsigned* release,
                                     int tid, unsigned seq)
{
    __syncthreads();
    if (tid == 0) {
        asm volatile("s_waitcnt vmcnt(0) lgkmcnt(0)" ::: "memory");
        unsigned prev = __hip_atomic_fetch_add(cnt, 1u, __ATOMIC_RELAXED,
                                               __HIP_MEMORY_SCOPE_AGENT);
        if (prev == (unsigned)NBLK * seq - 1u) {
            __hip_atomic_store(release, seq, __ATOMIC_RELAXED,
                               __HIP_MEMORY_SCOPE_AGENT);
        } else {
            while (__hip_atomic_load(release, __ATOMIC_RELAXED,
                                     __HIP_MEMORY_SCOPE_AGENT) < seq)
                __builtin_amdgcn_s_sleep(1);
        }
        asm volatile("" ::: "memory");
    }
    __syncthreads();
}

// ---------------- prep: transpose x & W_out, init state ----------------
__global__ __launch_bounds__(256)
void prep_kernel(const float* __restrict__ x, const float* __restrict__ Wout,
                 float* __restrict__ ws)
{
    int g = blockIdx.x * 256 + threadIdx.x;
    if (g < SZ_XT) {                       // xT[t][k][b] = x[b][t][k]
        int b = g & 31, k = (g >> 5) & 255, t = g >> 13;
        ws[OFF_XT + g] = x[b * (S_*I_) + t * I_ + k];
        return;
    }
    g -= SZ_XT;
    if (g < SZ_WOT) {                      // WoT[k][o] = W_out[o][k]
        int o = g & 255, k = g >> 8;
        ws[OFF_WOT + g] = Wout[o * (H_ + C_) + k];
        return;
    }
    g -= SZ_WOT;
    if (g < HB)      { ws[OFF_HA + g] = 0.f;   return; }   // h slot 0
    g -= HB;
    if (g < C_*B_)   { ws[OFF_RA + g] = 0.f;   return; }   // r slot 0
    g -= C_*B_;
    if (g < SZ_CT)   { ws[OFF_CT + g] = 0.f;   return; }   // c
    g -= SZ_CT;
    if (g < SZ_M)    { ws[OFF_M  + g] = 0.01f; return; }   // M
    g -= SZ_M;
    if (g < 2*SZ_W)  { ws[OFF_WR + g] = 0.f;   return; }   // unused slots
    g -= 2*SZ_W;
    if (g < SZ_BAR)  { ws[OFF_BAR + g] = 0.f;  return; }   // cnt/release
}

// ---------------- persistent sequential loop (cooperative-style) -----------
// 256 blocks x 512 threads, 1 block/CU, 2 fence-free syncs/step.
// Block bi: ug = bi>>1 owns units [4ug,4ug+4) (16 gate rows in LDS), bh = bi&1
// owns batches [16bh,16bh+16). Blocks 0..31 do ALL of phase B for batch bi;
// p, w_r, w_w live in LDS for the whole kernel.
__global__ __launch_bounds__(512)
void ntm_loop(const float* __restrict__ Wih, const float* __restrict__ Whh,
              const float* __restrict__ bl,  const float* __restrict__ Whead,
              const float* __restrict__ bhead, float* __restrict__ ws)
{
    float* xT  = ws + OFF_XT;
    float* hA  = ws + OFF_HA;
    float* rA  = ws + OFF_RA;
    float* cT  = ws + OFF_CT;
    float* Mem = ws + OFF_M;
    unsigned* cnt     = (unsigned*)(ws + OFF_BAR);
    unsigned* release = (unsigned*)(ws + OFF_BAR + 64);

    __shared__ float Wt[K_ * 18];     // gate rows transposed, stride 18
    __shared__ float p_lds[P_];
    __shared__ float sbuf[128];
    __shared__ float wtmp[128];
    __shared__ float wldsR[128];      // persistent w_r (blocks 0..31)
    __shared__ float wldsW[128];      // persistent w_w
    __shared__ float h_lds[H_];       // phase-B h staging

    const int tid = threadIdx.x;
    const int bi  = blockIdx.x;
    const int ug  = bi >> 1;
    const int bh  = bi & 1;

    // Load this block's 16 gate rows into LDS (once per launch).
    for (int idx = tid; idx < K_ * 16; idx += 512) {
        int rl = idx & 15, k = idx >> 4;
        int row = (rl & 3) * H_ + ug * 4 + (rl >> 2);
        float v = (k < I_ + C_) ? Wih[row * (I_ + C_) + k]
                                : Whh[row * H_ + (k - (I_ + C_))];
        Wt[k * 18 + rl] = v;
    }
    if (tid < N_) {                  // persistent addressing weights, w0 = e0
        wldsR[tid] = (tid == 0) ? 1.f : 0.f;
        wldsW[tid] = (tid == 0) ? 1.f : 0.f;
    }

    const int pair = tid >> 5;        // 0..15
    const int ks   = tid & 31;        // split-K lane
    const int rg   = pair >> 2;       // u_local 0..3
    const int bg   = pair & 3;        // batch quad 0..3
    const int b0   = bh * 16 + bg * 4;

    unsigned seq = 0;

    for (int t = 0; t < S_; ++t) {
        // ---------------- P1: gates GEMM + LSTM update -> h[t+1], c ----------------
        {
            float acc[4][4] = {{0,0,0,0},{0,0,0,0},{0,0,0,0},{0,0,0,0}};
            const float* xs = xT + (size_t)t * I_ * B_;
            const float* rs = rA + (size_t)t * C_ * B_;
            const float* hs = hA + (size_t)t * HB;
            if (t == 0) __syncthreads();   // cover Wt / wlds staging
            #pragma unroll
            for (int i = 0; i < 26; ++i) {
                const int k = ks + (i << 5);
                const float* ap;
                if (i < 8)       ap = xs + k * B_ + b0;
                else if (i < 10) ap = rs + (k - I_) * B_ + b0;
                else             ap = hs + (k - I_ - C_) * B_ + b0;
                const float4 a   = *(const float4*)ap;
                const float2 w01 = *(const float2*)&Wt[k * 18 + (rg << 2)];
                const float2 w23 = *(const float2*)&Wt[k * 18 + (rg << 2) + 2];
                const float wv[4] = {w01.x, w01.y, w23.x, w23.y};
                const float av[4] = {a.x, a.y, a.z, a.w};
                #pragma unroll
                for (int j = 0; j < 4; ++j)
                    #pragma unroll
                    for (int bb = 0; bb < 4; ++bb)
                        acc[j][bb] += wv[j] * av[bb];
            }
            #pragma unroll
            for (int j = 0; j < 4; ++j)
                #pragma unroll
                for (int bb = 0; bb < 4; ++bb) {
                    float v = acc[j][bb];
                    v += __shfl_xor(v, 16, 64);
                    v += __shfl_xor(v, 8, 64);
                    v += __shfl_xor(v, 4, 64);
                    v += __shfl_xor(v, 2, 64);
                    v += __shfl_xor(v, 1, 64);
                    acc[j][bb] = v;
                }
            if (ks == 0) {
                const int unit = ug * 4 + rg;
                #pragma unroll
                for (int bb = 0; bb < 4; ++bb) {
                    const int b = b0 + bb;
                    float gi = acc[0][bb] + bl[unit];
                    float gf = acc[1][bb] + bl[H_ + unit];
                    float gg = acc[2][bb] + bl[2 * H_ + unit];
                    float go = acc[3][bb] + bl[3 * H_ + unit];
                    float cN = sigm(gf) * cT[unit * B_ + b] + sigm(gi) * tanhf(gg);
                    float hN = sigm(go) * tanhf(cN);
                    cT[unit * B_ + b] = cN;   // private: normal store
                    // shared: publish write-through to L3
                    __hip_atomic_store(&hA[(size_t)(t + 1) * HB + unit * B_ + b],
                                       hN, __ATOMIC_RELAXED,
                                       __HIP_MEMORY_SCOPE_AGENT);
                }
            }
        }
        gbar(cnt, release, tid, ++seq);

        // ---- Phase B (blocks 0..31): head GEMM + addressing + write + read ----
        if (bi < B_) {
            const int b = bi;
            float* Mb = Mem + (size_t)b * N_ * C_;
            const float* hs = hA + (size_t)(t + 1) * HB;

            // stage h[:,b] into LDS (agent-scope loads: read from L3, no stale L1/L2)
            h_lds[tid] = __hip_atomic_load(&hs[tid * B_ + b], __ATOMIC_RELAXED,
                                           __HIP_MEMORY_SCOPE_AGENT);
            __syncthreads();

            // head GEMM: p = W_head @ h + b_head, 2 threads per row (split-K)
            {
                const int sub  = tid & 1;        // k-half
                const int row0 = tid >> 1;       // 0..255
                const float* hb = &h_lds[sub * 256];
                {
                    const float* wrow = Whead + row0 * H_ + sub * 256;
                    float acc = 0.f;
                    #pragma unroll 8
                    for (int k2 = 0; k2 < 256; k2 += 4) {
                        const float4 w4 = *(const float4*)&wrow[k2];
                        acc += w4.x * hb[k2] + w4.y * hb[k2 + 1]
                             + w4.z * hb[k2 + 2] + w4.w * hb[k2 + 3];
                    }
                    acc += __shfl_xor(acc, 1, 64);
                    if (sub == 0) p_lds[row0] = acc + bhead[row0];
                }
                if (row0 < P_ - 256) {           // rows 256..267
                    const int row1 = row0 + 256;
                    const float* wrow = Whead + row1 * H_ + sub * 256;
                    float acc = 0.f;
                    #pragma unroll 8
                    for (int k2 = 0; k2 < 256; k2 += 4) {
                        const float4 w4 = *(const float4*)&wrow[k2];
                        acc += w4.x * hb[k2] + w4.y * hb[k2 + 1]
                             + w4.z * hb[k2 + 2] + w4.w * hb[k2 + 3];
                    }
                    acc += __shfl_xor(acc, 1, 64);
                    if (sub == 0) p_lds[row1] = acc + bhead[row1];
                }
            }
            __syncthreads();

            // addressing: pass 0 read head (params at 0), pass 1 write head (70)
            for (int pass = 0; pass < 2; ++pass) {
                const int o = pass ? 70 : 0;
                const float beta  = splus(p_lds[o + 64]);
                const float gate  = sigm(p_lds[o + 65]);
                float sa = p_lds[o + 66], sbv = p_lds[o + 67], sc = p_lds[o + 68];
                float sm3 = fmaxf(sa, fmaxf(sbv, sc));
                float ea = expf(sa - sm3), eb = expf(sbv - sm3), ec = expf(sc - sm3);
                float es3 = ea + eb + ec;
                const float s0 = ea / es3, s1 = eb / es3, s2 = ec / es3;
                const float gamma = 1.f + splus(p_lds[o + 69]);
                float kk = 0.f;
                #pragma unroll 8
                for (int c = 0; c < C_; ++c) { float kv = p_lds[o + c]; kk += kv * kv; }
                const float knorm = sqrtf(kk) + EPSX;

                const int n = tid;
                float z = 0.f, ev = 0.f;
                if (tid < N_) {
                    float dot = 0.f, mm = 0.f;
                    #pragma unroll
                    for (int c = 0; c < C_; c += 4) {
                        float4 m4 = *(const float4*)&Mb[n * C_ + c];
                        dot += m4.x * p_lds[o + c]     + m4.y * p_lds[o + c + 1]
                             + m4.z * p_lds[o + c + 2] + m4.w * p_lds[o + c + 3];
                        mm  += m4.x * m4.x + m4.y * m4.y + m4.z * m4.z + m4.w * m4.w;
                    }
                    z = beta * (dot / ((sqrtf(mm) + EPSX) * knorm));
                }
                if (tid < N_) sbuf[tid] = z;
                __syncthreads();
                for (int st = 64; st > 0; st >>= 1) {
                    if (tid < st && tid + st < N_) sbuf[tid] = fmaxf(sbuf[tid], sbuf[tid + st]);
                    __syncthreads();
                }
                const float zmax = sbuf[0];
                __syncthreads();
                if (tid < N_) { ev = expf(z - zmax); sbuf[tid] = ev; }
                __syncthreads();
                for (int st = 64; st > 0; st >>= 1) {
                    if (tid < st && tid + st < N_) sbuf[tid] += sbuf[tid + st];
                    __syncthreads();
                }
                const float esum = sbuf[0];
                __syncthreads();
                if (tid < N_) {
                    float wc = ev / esum;
                    float wprev_v = pass ? wldsW[n] : wldsR[n];
                    wtmp[n] = gate * wc + (1.f - gate) * wprev_v;
                }
                __syncthreads();
                float wp = 0.f;
                if (tid < N_) {
                    float wsft = s0 * wtmp[(n + 1) & (N_-1)] + s1 * wtmp[n]
                               + s2 * wtmp[(n - 1) & (N_-1)];
                    wp = powf(wsft + EPSX, gamma);
                    sbuf[tid] = wp;
                }
                __syncthreads();
                for (int st = 64; st > 0; st >>= 1) {
                    if (tid < st && tid + st < N_) sbuf[tid] += sbuf[tid + st];
                    __syncthreads();
                }
                const float psum = sbuf[0];
                __syncthreads();
                if (tid < N_) {
                    float wn = wp / psum;
                    if (pass) wldsW[n] = wn; else wldsR[n] = wn;
                }
                __syncthreads();
            }

            // M = M*(1 - w_w e) + w_w a   (private: normal access)
            for (int idx = tid; idx < (N_ * C_) / 4; idx += 512) {
                const int n = idx >> 4;
                const int c = (idx & 15) << 2;
                const float wwn = wldsW[n];
                float4 m4 = *(float4*)&Mb[n * C_ + c];
                m4.x = m4.x * (1.f - wwn * sigm(p_lds[140 + c]))     + wwn * p_lds[204 + c];
                m4.y = m4.y * (1.f - wwn * sigm(p_lds[140 + c + 1])) + wwn * p_lds[204 + c + 1];
                m4.z = m4.z * (1.f - wwn * sigm(p_lds[140 + c + 2])) + wwn * p_lds[204 + c + 2];
                m4.w = m4.w * (1.f - wwn * sigm(p_lds[140 + c + 3])) + wwn * p_lds[204 + c + 3];
                *(float4*)&Mb[n * C_ + c] = m4;
            }
            __syncthreads();

            // r = w_r @ M_new  -> publish to L3
            {
                const int c = tid >> 3, ns = tid & 7;
                float acc = 0.f;
                #pragma unroll
                for (int i = 0; i < 16; ++i) {
                    const int n = ns + 8 * i;
                    acc += wldsR[n] * Mb[n * C_ + c];
                }
                acc += __shfl_xor(acc, 4, 64);
                acc += __shfl_xor(acc, 2, 64);
                acc += __shfl_xor(acc, 1, 64);
                if (ns == 0)
                    __hip_atomic_store(&rA[(size_t)(t + 1) * C_ * B_ + c * B_ + b],
                                       acc, __ATOMIC_RELAXED,
                                       __HIP_MEMORY_SCOPE_AGENT);
            }
        }
        gbar(cnt, release, tid, ++seq);
    }
}

// ---------------- final output GEMM ----------------
__global__ __launch_bounds__(256)
void out_kernel(const float* __restrict__ ws, const float* __restrict__ bout,
                float* __restrict__ out)
{
    __shared__ float actL[(H_ + C_) * 16];   // 36,864 B
    const float* hA  = ws + OFF_HA;
    const float* rA  = ws + OFF_RA;
    const float* WoT = ws + OFF_WOT;
    const int t   = blockIdx.x >> 1;
    const int bh  = blockIdx.x & 1;
    const int tid = threadIdx.x;

    for (int idx = tid; idx < (H_ + C_) * 16; idx += 256) {
        const int k = idx >> 4, bl2 = idx & 15, b = bh * 16 + bl2;
        float v = (k < H_) ? hA[(size_t)(t + 1) * HB + k * B_ + b]
                           : rA[(size_t)(t + 1) * C_ * B_ + (k - H_) * B_ + b];
        actL[k * 16 + bl2] = v;
    }
    __syncthreads();

    const int ot = tid & 63, bt = tid >> 6;
    const int o0 = ot * 4, bl0 = bt * 4;
    float acc[4][4] = {{0,0,0,0},{0,0,0,0},{0,0,0,0},{0,0,0,0}};
    for (int k = 0; k < H_ + C_; ++k) {
        const float4 w4 = *(const float4*)&WoT[k * O_ + o0];
        const float4 a4 = *(const float4*)&actL[k * 16 + bl0];
        const float wv[4] = {w4.x, w4.y, w4.z, w4.w};
        const float av[4] = {a4.x, a4.y, a4.z, a4.w};
        #pragma unroll
        for (int j = 0; j < 4; ++j)
            #pragma unroll
            for (int bb = 0; bb < 4; ++bb)
                acc[j][bb] += wv[j] * av[bb];
    }
    const float4 bo = *(const float4*)&bout[o0];
    #pragma unroll
    for (int bb = 0; bb < 4; ++bb) {
        const int b = bh * 16 + bl0 + bb;
        float4 res;
        res.x = acc[0][bb] + bo.x;
        res.y = acc[1][bb] + bo.y;
        res.z = acc[2][bb] + bo.z;
        res.w = acc[3][bb] + bo.w;
        *(float4*)&out[((size_t)b * S_ + t) * O_ + o0] = res;
    }
}

extern "C" void kernel_launch(void* const* d_in, const int* in_sizes, int n_in,
                              void* d_out, int out_size, void* d_ws, size_t ws_size,
                              hipStream_t stream)
{
    const float* x    = (const float*)d_in[0];
    const float* Wih  = (const float*)d_in[1];
    const float* Whh  = (const float*)d_in[2];
    const float* bl   = (const float*)d_in[3];
    const float* Whd  = (const float*)d_in[4];
    const float* bhd  = (const float*)d_in[5];
    const float* Wout = (const float*)d_in[6];
    const float* bout = (const float*)d_in[7];
    float* ws  = (float*)d_ws;    // needs 29.1 MB
    float* out = (float*)d_out;

    prep_kernel<<<9962, 256, 0, stream>>>(x, Wout, ws);

    void* args[] = { (void*)&Wih, (void*)&Whh, (void*)&bl,
                     (void*)&Whd, (void*)&bhd, (void*)&ws };
    (void)hipLaunchCooperativeKernel((void*)ntm_loop, dim3(256), dim3(512), args, 0, stream);

    out_kernel<<<512, 256, 0, stream>>>(ws, bout, out);
}